// Round 18
// baseline (151.942 us; speedup 1.0000x reference)
//
#include <hip/hip_runtime.h>
#include <hip/hip_bf16.h>
#include <cstdint>
#include <cstddef>

#define DDIM 1024
#define NHEADS 16
#define HDIM 64
#define NSEQ 2048
#define NTOK 4096
#define QSCALE 0.18033688011112042f  // 0.125 * log2(e): folded into Q projection

typedef float f32x4 __attribute__((ext_vector_type(4)));
typedef float f32x16 __attribute__((ext_vector_type(16)));
typedef __bf16 bf16x8 __attribute__((ext_vector_type(8)));
typedef unsigned short u16x8 __attribute__((ext_vector_type(8)));

typedef __attribute__((address_space(1))) const unsigned int gq_t;
typedef __attribute__((address_space(3))) unsigned int lq_t;

__device__ __forceinline__ unsigned short f2bf(float f) {
    union { float f; unsigned int u; } v; v.f = f;
    unsigned int u = v.u;
    u += 0x7FFFu + ((u >> 16) & 1u);
    return (unsigned short)(u >> 16);
}

// raw v_exp_f32 = 2^x ; s_nop covers the trans-op hazard for the consumer
__device__ __forceinline__ float exp2_fast(float x) {
    float r;
    asm("v_exp_f32 %0, %1\n\ts_nop 0" : "=v"(r) : "v"(x));
    return r;
}

__device__ __forceinline__ unsigned cvtpk_bf16(float lo, float hi) {
    unsigned r;
    asm("v_cvt_pk_bf16_f32 %0, %1, %2" : "=v"(r) : "v"(lo), "v"(hi));
    return r;
}

#define PSWAP(a, b) asm("v_permlane32_swap_b32 %0, %1" : "+v"(a), "+v"(b))

// ---------------- fp32 -> bf16 converts (ONE launch, 7 z-slices) ----------
__global__ __launch_bounds__(256) void cvt_all_kernel(
    const float* __restrict__ a0, const float* __restrict__ a1,
    const float* __restrict__ a2, const float* __restrict__ a3,
    const float* __restrict__ a4, const float* __restrict__ a5,
    const float* __restrict__ a6, unsigned short* __restrict__ d0,
    unsigned short* __restrict__ d1, unsigned short* __restrict__ d2,
    unsigned short* __restrict__ d3, unsigned short* __restrict__ d4,
    unsigned short* __restrict__ d5, unsigned short* __restrict__ d6,
    int tok8, int w8) {
    int z = blockIdx.z;
    const float* s = z == 0 ? a0 : z == 1 ? a1 : z == 2 ? a2 : z == 3 ? a3
                     : z == 4 ? a4 : z == 5 ? a5 : a6;
    unsigned short* d = z == 0 ? d0 : z == 1 ? d1 : z == 2 ? d2 : z == 3 ? d3
                        : z == 4 ? d4 : z == 5 ? d5 : d6;
    int n8 = (z < 3) ? tok8 : w8;
    int i = blockIdx.x * 256 + threadIdx.x;
    if (i >= n8) return;
    const float4* s4 = (const float4*)s + (size_t)i * 2;
    float4 a = s4[0], b = s4[1];
    unsigned short o[8] __attribute__((aligned(16)));
    o[0] = f2bf(a.x); o[1] = f2bf(a.y); o[2] = f2bf(a.z); o[3] = f2bf(a.w);
    o[4] = f2bf(b.x); o[5] = f2bf(b.y); o[6] = f2bf(b.z); o[7] = f2bf(b.w);
    *(u16x8*)(d + (size_t)i * 8) = *(const u16x8*)o;
}

// ---------------- GEMM: C[m,n] = sum_k A[m,k]*W[n,k] + bias[n] ----------------
// r17 structure with tile 128x64 (BK=32): grid per z = 16n x 32m = 512 blocks
// -> 6 blocks/CU = 24 waves/CU (occupancy lever; 128x128 was grid-capped at
// 3 blocks/CU / 31%). 4 waves (2x2), 64x32 per wave, acc[4][2], 8 MFMA/iter.
// XCD swizzle: f=x+16y, swz=(f&7)*64+(f>>3) -> per-XCD 4 m-panels x 16 n
// (A 1MB + B 2MB <= 4MB L2, bijective).
// mode 0: Q -> bf16 scaled; 1: K head-major; 2: V token-major; 3: f32 out.
__device__ __forceinline__ void gemm_body(const unsigned short* __restrict__ A,
                                          const unsigned short* __restrict__ W,
                                          const float* __restrict__ bias,
                                          int mode, void* __restrict__ Cout) {
    __shared__ __align__(16) unsigned short As[128 * 32];
    __shared__ __align__(16) unsigned short Bs[64 * 32];
    const int tid = threadIdx.x, lane = tid & 63, wid = tid >> 6;
    const int r = lane & 15, g = lane >> 4;
    const int f = blockIdx.y * 16 + blockIdx.x;    // 0..511 per z
    const int swz = (f & 7) * 64 + (f >> 3);
    const int mbase = (swz >> 4) * 128;
    const int nbase = (swz & 15) * 64;
    const int wm = (wid >> 1) * 64, wn = (wid & 1) * 32;

    f32x4 zero = {0.f, 0.f, 0.f, 0.f};
    f32x4 acc[4][2];
#pragma unroll
    for (int mi = 0; mi < 4; ++mi)
#pragma unroll
        for (int ni = 0; ni < 2; ++ni) acc[mi][ni] = zero;

    for (int kt = 0; kt < 1024; kt += 32) {
        __syncthreads();
#pragma unroll
        for (int j = 0; j < 2; ++j) {
            int ub = wid * 64 + j * 256;  // wave-uniform 16B-unit base
            int uu = ub + lane;
            const unsigned short* ga =
                A + (size_t)(mbase + (uu >> 2)) * 1024 + kt + (uu & 3) * 8;
            __builtin_amdgcn_global_load_lds((gq_t*)ga, (lq_t*)(As + ub * 8), 16, 0, 0);
        }
        {
            int ub = wid * 64;
            int uu = ub + lane;
            const unsigned short* gb =
                W + (size_t)(nbase + (uu >> 2)) * 1024 + kt + (uu & 3) * 8;
            __builtin_amdgcn_global_load_lds((gq_t*)gb, (lq_t*)(Bs + ub * 8), 16, 0, 0);
        }
        __syncthreads();
        bf16x8 af[4], bf[2];
#pragma unroll
        for (int mi = 0; mi < 4; ++mi)
            af[mi] = *(const bf16x8*)(As + (wm + mi * 16 + r) * 32 + g * 8);
#pragma unroll
        for (int ni = 0; ni < 2; ++ni)
            bf[ni] = *(const bf16x8*)(Bs + (wn + ni * 16 + r) * 32 + g * 8);
        __builtin_amdgcn_s_setprio(1);
#pragma unroll
        for (int mi = 0; mi < 4; ++mi)
#pragma unroll
            for (int ni = 0; ni < 2; ++ni)
                acc[mi][ni] = __builtin_amdgcn_mfma_f32_16x16x32_bf16(
                    af[mi], bf[ni], acc[mi][ni], 0, 0, 0);
        __builtin_amdgcn_s_setprio(0);
    }
    // epilogue: C row = (lane>>4)*4 + reg, col = lane&15
#pragma unroll
    for (int mi = 0; mi < 4; ++mi) {
#pragma unroll
        for (int ni = 0; ni < 2; ++ni) {
            int c = nbase + wn + ni * 16 + r;
            float bv = bias[c];
#pragma unroll
            for (int rr = 0; rr < 4; ++rr) {
                int m = mbase + wm + mi * 16 + g * 4 + rr;
                float val = acc[mi][ni][rr] + bv;
                if (mode == 0) {
                    ((unsigned short*)Cout)[(size_t)m * 1024 + c] = f2bf(val * QSCALE);
                } else if (mode == 1) {
                    size_t addr = ((size_t)((m >> 11) * 16 + (c >> 6)) * 2048 +
                                   (size_t)(m & 2047)) * 64 + (c & 63);
                    ((unsigned short*)Cout)[addr] = f2bf(val);
                } else if (mode == 2) {
                    ((unsigned short*)Cout)[(size_t)m * 1024 + c] = f2bf(val);
                } else {
                    ((float*)Cout)[(size_t)m * 1024 + c] = val;
                }
            }
        }
    }
}

__global__ __launch_bounds__(256) void gemm_qkv_kernel(
    const unsigned short* __restrict__ qb, const unsigned short* __restrict__ kb,
    const unsigned short* __restrict__ vb, const unsigned short* __restrict__ Wq,
    const unsigned short* __restrict__ Wk, const unsigned short* __restrict__ Wv,
    const float* __restrict__ bq, const float* __restrict__ bk,
    const float* __restrict__ bv, unsigned short* __restrict__ Qp,
    unsigned short* __restrict__ Kp, unsigned short* __restrict__ Vp) {
    int z = blockIdx.z;
    const unsigned short* A = (z == 0) ? qb : (z == 1) ? kb : vb;
    const unsigned short* W = (z == 0) ? Wq : (z == 1) ? Wk : Wv;
    const float* bias = (z == 0) ? bq : (z == 1) ? bk : bv;
    unsigned short* C = (z == 0) ? Qp : (z == 1) ? Kp : Vp;
    gemm_body(A, W, bias, z, C);
}

__global__ __launch_bounds__(256) void gemm_out_kernel(
    const unsigned short* __restrict__ AO, const unsigned short* __restrict__ Wo,
    const float* __restrict__ bo, float* __restrict__ out) {
    gemm_body(AO, Wo, bo, 3, out);
}

// ---------------- V transpose: [4096 tok][1024] -> [32 bh][64 d][2048 n] ----
__global__ __launch_bounds__(256) void vtrans_kernel(
    const unsigned short* __restrict__ Vp, unsigned short* __restrict__ Vt) {
    __shared__ __align__(16) unsigned short T[64 * 80];
    const int tid = threadIdx.x;
    const int n0 = blockIdx.x * 64, bh = blockIdx.y;
    const int b = bh >> 4, h = bh & 15;
    const unsigned short* src = Vp + (size_t)(b * NSEQ + n0) * DDIM + h * HDIM;
#pragma unroll
    for (int j = 0; j < 2; ++j) {
        int idx = j * 256 + tid;
        int n = idx >> 3, c = (idx & 7) * 8;
        u16x8 val = *(const u16x8*)(src + (size_t)n * DDIM + c);
        *(u16x8*)(&T[n * 80 + c]) = val;
    }
    __syncthreads();
    unsigned short* dst = Vt + (size_t)bh * HDIM * NSEQ + n0;
#pragma unroll
    for (int j = 0; j < 2; ++j) {
        int idx = j * 256 + tid;
        int d = idx >> 3, nn = (idx & 7) * 8, rot = idx & 7;
        unsigned short o[8] __attribute__((aligned(16)));
#pragma unroll
        for (int e0 = 0; e0 < 8; ++e0) {
            int e = (e0 + rot) & 7;  // stagger lanes across banks
            o[e] = T[(nn + e) * 80 + d];
        }
        *(u16x8*)(dst + (size_t)d * NSEQ + nn) = *(const u16x8*)o;
    }
}

// ---------------- flash attention: 32x32 swapped + LDS fragment staging ----
// r8/r16/r17's exact kernel (best build): double buffer, STAGE -> vmcnt(4) ->
// barrier -> [QK0;QK1][SM0;SM1][PV0;PV1] -> barrier, split-stream
// max-tracking, flash-merge at end.
__global__ __launch_bounds__(256, 2) void attn_kernel(
    const unsigned short* __restrict__ Qp,   // [4096][1024], pre-scaled
    const unsigned short* __restrict__ Kh,   // [32][2048][64]
    const unsigned short* __restrict__ Vt,   // [32][64][2048]
    unsigned short* __restrict__ AO) {       // [4096][1024]
    __shared__ __align__(16) unsigned short Ks[2][4096];  // 8 frags x 512 elem
    __shared__ __align__(16) unsigned short Vs[2][4096];

    const int tid = threadIdx.x, lane = tid & 63, wid = tid >> 6;
    const int q31 = lane & 31, hi = lane >> 5;

    // XCD swizzle: 4 consecutive bh per XCD (2 MB K+V -> L2-resident)
    int bid = blockIdx.x;
    int swz = (bid & 7) * 64 + (bid >> 3);
    const int bh = swz >> 4, b = bh >> 4, h = bh & 15;
    const int qbase = ((swz & 15) * 4 + wid) * 32;

    const unsigned short* Kt = Kh + (size_t)bh * (NSEQ * HDIM);
    const unsigned short* Vb = Vt + (size_t)bh * (HDIM * NSEQ);

    // Q fragments (B-operand): lane q-col = q31, k = 16t + 8hi + e
    bf16x8 qf[4];
    {
        const unsigned short* qp =
            Qp + (size_t)(b * NSEQ + qbase + q31) * DDIM + h * HDIM + hi * 8;
#pragma unroll
        for (int t = 0; t < 4; ++t) qf[t] = *(const bf16x8*)(qp + t * 16);
    }

    // staging source offsets (fragment-order permutation), per-lane constants.
    const size_t koff0 = (size_t)q31 * HDIM + (wid & 3) * 16 + hi * 8;
    const size_t koff1 = koff0 + 32 * HDIM;
    const size_t voff0 =
        (size_t)q31 * NSEQ + ((wid >> 1) & 1) * 32 + (wid & 1) * 16 + hi * 8;
    const size_t voff1 = voff0 + (size_t)32 * NSEQ;
    const int lb0 = wid * 512, lb1 = wid * 512 + 2048;

    auto STAGE = [&](int buf, int kv0) {
        const unsigned short* kbase = Kt + (size_t)kv0 * HDIM;
        __builtin_amdgcn_global_load_lds((gq_t*)(kbase + koff0),
                                         (lq_t*)(&Ks[buf][lb0]), 16, 0, 0);
        __builtin_amdgcn_global_load_lds((gq_t*)(kbase + koff1),
                                         (lq_t*)(&Ks[buf][lb1]), 16, 0, 0);
        const unsigned short* vbase = Vb + kv0;
        __builtin_amdgcn_global_load_lds((gq_t*)(vbase + voff0),
                                         (lq_t*)(&Vs[buf][lb0]), 16, 0, 0);
        __builtin_amdgcn_global_load_lds((gq_t*)(vbase + voff1),
                                         (lq_t*)(&Vs[buf][lb1]), 16, 0, 0);
    };

    // two independent streams (even/odd half-tiles)
    f32x16 oA0, oB0, oA1, oB1;
#pragma unroll
    for (int i = 0; i < 16; ++i) {
        oA0[i] = 0.f; oB0[i] = 0.f; oA1[i] = 0.f; oB1[i] = 0.f;
    }
    float m0 = -3.0e38f, l0 = 0.f, m1 = -3.0e38f, l1 = 0.f;

    union PB { unsigned u[4]; bf16x8 v; };

    // phase 1: S^T = K^T-tile x Q (4 MFMA), per half-tile s
    auto QK = [&](int cur, int s) -> f32x16 {
        const unsigned short* kf = &Ks[cur][s * 2048 + lane * 8];
        f32x16 st;
#pragma unroll
        for (int i = 0; i < 16; ++i) st[i] = 0.f;
#pragma unroll
        for (int t = 0; t < 4; ++t)
            st = __builtin_amdgcn_mfma_f32_32x32x16_bf16(
                *(const bf16x8*)(kf + t * 512), qf[t], st, 0, 0, 0);
        return st;
    };

    // phase 2: online softmax on one stream -> packed P fragments
    auto SM = [&](const f32x16& st, float& m, float& l, f32x16& oA, f32x16& oB,
                  PB& P0, PB& P1) {
        float m8[8], m4[4];
#pragma unroll
        for (int j = 0; j < 8; ++j) m8[j] = fmaxf(st[2 * j], st[2 * j + 1]);
#pragma unroll
        for (int j = 0; j < 4; ++j) m4[j] = fmaxf(m8[2 * j], m8[2 * j + 1]);
        float pm = fmaxf(fmaxf(m4[0], m4[1]), fmaxf(m4[2], m4[3]));
        pm = fmaxf(pm, __shfl_xor(pm, 32, 64));

        // defer-max (T13): rescale only when max grew past THR=8 (log2 domain)
        if (__any(pm - m > 8.0f)) {
            float mn = fmaxf(m, pm);
            float al = exp2_fast(m - mn);
            m = mn;
            l *= al;
#pragma unroll
            for (int i = 0; i < 16; ++i) { oA[i] *= al; oB[i] *= al; }
        }

        float p[16];
#pragma unroll
        for (int i = 0; i < 16; ++i) p[i] = exp2_fast(st[i] - m);
        float s8[8], s4[4];
#pragma unroll
        for (int j = 0; j < 8; ++j) s8[j] = p[2 * j] + p[2 * j + 1];
#pragma unroll
        for (int j = 0; j < 4; ++j) s4[j] = s8[2 * j] + s8[2 * j + 1];
        float rs = (s4[0] + s4[1]) + (s4[2] + s4[3]);
        rs += __shfl_xor(rs, 32, 64);
        l += rs;

        unsigned w0 = cvtpk_bf16(p[0], p[1]), w1 = cvtpk_bf16(p[2], p[3]);
        unsigned w2 = cvtpk_bf16(p[4], p[5]), w3 = cvtpk_bf16(p[6], p[7]);
        unsigned w4 = cvtpk_bf16(p[8], p[9]), w5 = cvtpk_bf16(p[10], p[11]);
        unsigned w6 = cvtpk_bf16(p[12], p[13]), w7 = cvtpk_bf16(p[14], p[15]);
        PSWAP(w0, w2); PSWAP(w1, w3); PSWAP(w4, w6); PSWAP(w5, w7);
        P0.u[0] = w0; P0.u[1] = w1; P0.u[2] = w2; P0.u[3] = w3;  // kv 8hi+0..7
        P1.u[0] = w4; P1.u[1] = w5; P1.u[2] = w6; P1.u[3] = w7;  // kv 16+8hi+..
    };

    // phase 3: O^T += V^T-tile x P^T (4 MFMA)
    auto PV = [&](int cur, int s, const PB& P0, const PB& P1, f32x16& oA,
                  f32x16& oB) {
        const unsigned short* vf0 = &Vs[cur][s * 1024 + lane * 8];          // dh=0
        const unsigned short* vf1 = &Vs[cur][2048 + s * 1024 + lane * 8];   // dh=1
        oA = __builtin_amdgcn_mfma_f32_32x32x16_bf16(
            *(const bf16x8*)(vf0), P0.v, oA, 0, 0, 0);
        oA = __builtin_amdgcn_mfma_f32_32x32x16_bf16(
            *(const bf16x8*)(vf0 + 512), P1.v, oA, 0, 0, 0);
        oB = __builtin_amdgcn_mfma_f32_32x32x16_bf16(
            *(const bf16x8*)(vf1), P0.v, oB, 0, 0, 0);
        oB = __builtin_amdgcn_mfma_f32_32x32x16_bf16(
            *(const bf16x8*)(vf1 + 512), P1.v, oB, 0, 0, 0);
    };

    STAGE(0, 0);
    int cur = 0;
    for (int it = 0; it < 32; ++it) {
        STAGE(cur ^ 1, ((it + 1) & 31) * 64);  // prefetch next (last wraps, unused)
        asm volatile("s_waitcnt vmcnt(4)" ::: "memory");  // cur's 4 loads done
        __builtin_amdgcn_s_barrier();
        __builtin_amdgcn_sched_barrier(0);
        // one scheduling region: two independent chains per phase
        __builtin_amdgcn_s_setprio(1);
        f32x16 st0 = QK(cur, 0);
        f32x16 st1 = QK(cur, 1);
        __builtin_amdgcn_s_setprio(0);
        PB P00, P01, P10, P11;
        SM(st0, m0, l0, oA0, oB0, P00, P01);
        SM(st1, m1, l1, oA1, oB1, P10, P11);
        __builtin_amdgcn_s_setprio(1);
        PV(cur, 0, P00, P01, oA0, oB0);
        PV(cur, 1, P10, P11, oA1, oB1);
        __builtin_amdgcn_s_setprio(0);
        __builtin_amdgcn_sched_barrier(0);
        asm volatile("" ::: "memory");
        __builtin_amdgcn_s_barrier();  // all waves done reading cur
        cur ^= 1;
    }

    // merge streams + epilogue: lane q holds O^T[d][q], d=(r&3)+8*(r>>2)+4*hi
    float mt = fmaxf(m0, m1);
    float a0 = exp2_fast(m0 - mt), a1 = exp2_fast(m1 - mt);
    float inv = 1.0f / (l0 * a0 + l1 * a1);
    unsigned short* op = AO + (size_t)(b * NSEQ + qbase + q31) * DDIM + h * HDIM;
#pragma unroll
    for (int r2 = 0; r2 < 16; ++r2) {
        int d = (r2 & 3) + 8 * (r2 >> 2) + 4 * hi;
        op[d] = f2bf((oA0[r2] * a0 + oA1[r2] * a1) * inv);
        op[d + 32] = f2bf((oB0[r2] * a0 + oB1[r2] * a1) * inv);
    }
}

// ---------------- host launch ----------------
extern "C" void kernel_launch(void* const* d_in, const int* in_sizes, int n_in,
                              void* d_out, int out_size, void* d_ws, size_t ws_size,
                              hipStream_t stream) {
    const float* q = (const float*)d_in[0];
    const float* k = (const float*)d_in[1];
    const float* v = (const float*)d_in[2];
    const float* Wq = (const float*)d_in[3];
    const float* bq = (const float*)d_in[4];
    const float* Wk = (const float*)d_in[5];
    const float* bk = (const float*)d_in[6];
    const float* Wv = (const float*)d_in[7];
    const float* bv = (const float*)d_in[8];
    const float* Wo = (const float*)d_in[9];
    const float* bo = (const float*)d_in[10];
    float* out = (float*)d_out;

    unsigned short* ws = (unsigned short*)d_ws;
    const size_t TOKD = (size_t)NTOK * DDIM;  // 4,194,304
    const size_t WD = (size_t)DDIM * DDIM;    // 1,048,576
    unsigned short* qb = ws;
    unsigned short* kb = qb + TOKD;
    unsigned short* vb = kb + TOKD;
    unsigned short* Wqb = vb + TOKD;
    unsigned short* Wkb = Wqb + WD;
    unsigned short* Wvb = Wkb + WD;
    unsigned short* Wob = Wvb + WD;
    unsigned short* Qp = Wob + WD;
    unsigned short* Kp = Qp + TOKD;   // head-major K
    unsigned short* Vp = Kp + TOKD;   // token-major V
    unsigned short* AOp = Vp + TOKD;
    unsigned short* Vtb = qb;  // reuse: qb dead after gemm_qkv; V^T lives here

    const int tok8 = (int)(TOKD / 8);  // 524288
    const int w8 = (int)(WD / 8);      // 131072
    cvt_all_kernel<<<dim3(tok8 / 256, 1, 7), 256, 0, stream>>>(
        q, k, v, Wq, Wk, Wv, Wo, qb, kb, vb, Wqb, Wkb, Wvb, Wob, tok8, w8);
    gemm_qkv_kernel<<<dim3(16, 32, 3), 256, 0, stream>>>(qb, kb, vb, Wqb, Wkb, Wvb,
                                                         bq, bk, bv, Qp, Kp, Vp);
    vtrans_kernel<<<dim3(32, 32), 256, 0, stream>>>(Vp, Vtb);
    attn_kernel<<<512, 256, 0, stream>>>(Qp, Kp, Vtb, AOp);
    gemm_out_kernel<<<dim3(16, 32), 256, 0, stream>>>(AOp, Wob, bo, out);
}

// Round 19
// 143.521 us; speedup vs baseline: 1.0587x; 1.0587x over previous
//
#include <hip/hip_runtime.h>
#include <hip/hip_bf16.h>
#include <cstdint>
#include <cstddef>

#define DDIM 1024
#define NHEADS 16
#define HDIM 64
#define NSEQ 2048
#define NTOK 4096
#define QSCALE 0.18033688011112042f  // 0.125 * log2(e): folded into Q projection

typedef float f32x4 __attribute__((ext_vector_type(4)));
typedef float f32x16 __attribute__((ext_vector_type(16)));
typedef __bf16 bf16x8 __attribute__((ext_vector_type(8)));
typedef unsigned short u16x8 __attribute__((ext_vector_type(8)));

typedef __attribute__((address_space(1))) const unsigned int gq_t;
typedef __attribute__((address_space(3))) unsigned int lq_t;

__device__ __forceinline__ unsigned short f2bf(float f) {
    union { float f; unsigned int u; } v; v.f = f;
    unsigned int u = v.u;
    u += 0x7FFFu + ((u >> 16) & 1u);
    return (unsigned short)(u >> 16);
}

// raw v_exp_f32 = 2^x ; s_nop covers the trans-op hazard for the consumer
__device__ __forceinline__ float exp2_fast(float x) {
    float r;
    asm("v_exp_f32 %0, %1\n\ts_nop 0" : "=v"(r) : "v"(x));
    return r;
}

__device__ __forceinline__ unsigned cvtpk_bf16(float lo, float hi) {
    unsigned r;
    asm("v_cvt_pk_bf16_f32 %0, %1, %2" : "=v"(r) : "v"(lo), "v"(hi));
    return r;
}

#define PSWAP(a, b) asm("v_permlane32_swap_b32 %0, %1" : "+v"(a), "+v"(b))

// ---------------- fp32 -> bf16 converts (ONE launch, 7 z-slices) ----------
__global__ __launch_bounds__(256) void cvt_all_kernel(
    const float* __restrict__ a0, const float* __restrict__ a1,
    const float* __restrict__ a2, const float* __restrict__ a3,
    const float* __restrict__ a4, const float* __restrict__ a5,
    const float* __restrict__ a6, unsigned short* __restrict__ d0,
    unsigned short* __restrict__ d1, unsigned short* __restrict__ d2,
    unsigned short* __restrict__ d3, unsigned short* __restrict__ d4,
    unsigned short* __restrict__ d5, unsigned short* __restrict__ d6,
    int tok8, int w8) {
    int z = blockIdx.z;
    const float* s = z == 0 ? a0 : z == 1 ? a1 : z == 2 ? a2 : z == 3 ? a3
                     : z == 4 ? a4 : z == 5 ? a5 : a6;
    unsigned short* d = z == 0 ? d0 : z == 1 ? d1 : z == 2 ? d2 : z == 3 ? d3
                        : z == 4 ? d4 : z == 5 ? d5 : d6;
    int n8 = (z < 3) ? tok8 : w8;
    int i = blockIdx.x * 256 + threadIdx.x;
    if (i >= n8) return;
    const float4* s4 = (const float4*)s + (size_t)i * 2;
    float4 a = s4[0], b = s4[1];
    unsigned short o[8] __attribute__((aligned(16)));
    o[0] = f2bf(a.x); o[1] = f2bf(a.y); o[2] = f2bf(a.z); o[3] = f2bf(a.w);
    o[4] = f2bf(b.x); o[5] = f2bf(b.y); o[6] = f2bf(b.z); o[7] = f2bf(b.w);
    *(u16x8*)(d + (size_t)i * 8) = *(const u16x8*)o;
}

// ---------------- GEMM: C[m,n] = sum_k A[m,k]*W[n,k] + bias[n] ----------------
// Best build (143.3 us): 128x128 tile, BK=32, 4 waves, global_load_lds
// staging, 2-barrier loop, XCD swizzle (each XCD owns 4 m-panels x 8 n-panels
// -> 3 MB working set L2-resident; FETCH 101->37 MB measured).
// mode 0: Q -> bf16 scaled; 1: K head-major; 2: V token-major; 3: f32 out.
__device__ __forceinline__ void gemm_body(const unsigned short* __restrict__ A,
                                          const unsigned short* __restrict__ W,
                                          const float* __restrict__ bias,
                                          int mode, void* __restrict__ Cout) {
    __shared__ __align__(16) unsigned short As[128 * 32];
    __shared__ __align__(16) unsigned short Bs[128 * 32];
    const int tid = threadIdx.x, lane = tid & 63, wid = tid >> 6;
    const int r = lane & 15, g = lane >> 4;
    // XCD swizzle: hardware f = y*8+x round-robins across 8 XCDs; remap so
    // each XCD gets 32 contiguous blocks = 4 m-panels x 8 n-panels.
    const int f = blockIdx.y * 8 + blockIdx.x;     // 0..255 per z
    const int swz = (f & 7) * 32 + (f >> 3);
    const int mbase = (swz >> 3) * 128;
    const int nbase = (swz & 7) * 128;
    const int wm = (wid >> 1) * 64, wn = (wid & 1) * 64;

    f32x4 zero = {0.f, 0.f, 0.f, 0.f};
    f32x4 acc[4][4];
#pragma unroll
    for (int mi = 0; mi < 4; ++mi)
#pragma unroll
        for (int ni = 0; ni < 4; ++ni) acc[mi][ni] = zero;

    for (int kt = 0; kt < 1024; kt += 32) {
        __syncthreads();
#pragma unroll
        for (int j = 0; j < 2; ++j) {
            int ub = wid * 64 + j * 256;  // wave-uniform 16B-unit base
            int uu = ub + lane;
            const unsigned short* ga =
                A + (size_t)(mbase + (uu >> 2)) * 1024 + kt + (uu & 3) * 8;
            __builtin_amdgcn_global_load_lds((gq_t*)ga, (lq_t*)(As + ub * 8), 16, 0, 0);
            const unsigned short* gb =
                W + (size_t)(nbase + (uu >> 2)) * 1024 + kt + (uu & 3) * 8;
            __builtin_amdgcn_global_load_lds((gq_t*)gb, (lq_t*)(Bs + ub * 8), 16, 0, 0);
        }
        __syncthreads();
        bf16x8 af[4], bf[4];
#pragma unroll
        for (int mi = 0; mi < 4; ++mi)
            af[mi] = *(const bf16x8*)(As + (wm + mi * 16 + r) * 32 + g * 8);
#pragma unroll
        for (int ni = 0; ni < 4; ++ni)
            bf[ni] = *(const bf16x8*)(Bs + (wn + ni * 16 + r) * 32 + g * 8);
#pragma unroll
        for (int mi = 0; mi < 4; ++mi)
#pragma unroll
            for (int ni = 0; ni < 4; ++ni)
                acc[mi][ni] = __builtin_amdgcn_mfma_f32_16x16x32_bf16(
                    af[mi], bf[ni], acc[mi][ni], 0, 0, 0);
    }
    // epilogue: C row = (lane>>4)*4 + reg, col = lane&15
#pragma unroll
    for (int mi = 0; mi < 4; ++mi) {
#pragma unroll
        for (int ni = 0; ni < 4; ++ni) {
            int c = nbase + wn + ni * 16 + r;
            float bv = bias[c];
#pragma unroll
            for (int rr = 0; rr < 4; ++rr) {
                int m = mbase + wm + mi * 16 + g * 4 + rr;
                float val = acc[mi][ni][rr] + bv;
                if (mode == 0) {
                    ((unsigned short*)Cout)[(size_t)m * 1024 + c] = f2bf(val * QSCALE);
                } else if (mode == 1) {
                    size_t addr = ((size_t)((m >> 11) * 16 + (c >> 6)) * 2048 +
                                   (size_t)(m & 2047)) * 64 + (c & 63);
                    ((unsigned short*)Cout)[addr] = f2bf(val);
                } else if (mode == 2) {
                    ((unsigned short*)Cout)[(size_t)m * 1024 + c] = f2bf(val);
                } else {
                    ((float*)Cout)[(size_t)m * 1024 + c] = val;
                }
            }
        }
    }
}

__global__ __launch_bounds__(256) void gemm_qkv_kernel(
    const unsigned short* __restrict__ qb, const unsigned short* __restrict__ kb,
    const unsigned short* __restrict__ vb, const unsigned short* __restrict__ Wq,
    const unsigned short* __restrict__ Wk, const unsigned short* __restrict__ Wv,
    const float* __restrict__ bq, const float* __restrict__ bk,
    const float* __restrict__ bv, unsigned short* __restrict__ Qp,
    unsigned short* __restrict__ Kp, unsigned short* __restrict__ Vp) {
    int z = blockIdx.z;
    const unsigned short* A = (z == 0) ? qb : (z == 1) ? kb : vb;
    const unsigned short* W = (z == 0) ? Wq : (z == 1) ? Wk : Wv;
    const float* bias = (z == 0) ? bq : (z == 1) ? bk : bv;
    unsigned short* C = (z == 0) ? Qp : (z == 1) ? Kp : Vp;
    gemm_body(A, W, bias, z, C);
}

__global__ __launch_bounds__(256) void gemm_out_kernel(
    const unsigned short* __restrict__ AO, const unsigned short* __restrict__ Wo,
    const float* __restrict__ bo, float* __restrict__ out) {
    gemm_body(AO, Wo, bo, 3, out);
}

// ---------------- V transpose: [4096 tok][1024] -> [32 bh][64 d][2048 n] ----
__global__ __launch_bounds__(256) void vtrans_kernel(
    const unsigned short* __restrict__ Vp, unsigned short* __restrict__ Vt) {
    __shared__ __align__(16) unsigned short T[64 * 80];
    const int tid = threadIdx.x;
    const int n0 = blockIdx.x * 64, bh = blockIdx.y;
    const int b = bh >> 4, h = bh & 15;
    const unsigned short* src = Vp + (size_t)(b * NSEQ + n0) * DDIM + h * HDIM;
#pragma unroll
    for (int j = 0; j < 2; ++j) {
        int idx = j * 256 + tid;
        int n = idx >> 3, c = (idx & 7) * 8;
        u16x8 val = *(const u16x8*)(src + (size_t)n * DDIM + c);
        *(u16x8*)(&T[n * 80 + c]) = val;
    }
    __syncthreads();
    unsigned short* dst = Vt + (size_t)bh * HDIM * NSEQ + n0;
#pragma unroll
    for (int j = 0; j < 2; ++j) {
        int idx = j * 256 + tid;
        int d = idx >> 3, nn = (idx & 7) * 8, rot = idx & 7;
        unsigned short o[8] __attribute__((aligned(16)));
#pragma unroll
        for (int e0 = 0; e0 < 8; ++e0) {
            int e = (e0 + rot) & 7;  // stagger lanes across banks
            o[e] = T[(nn + e) * 80 + d];
        }
        *(u16x8*)(dst + (size_t)d * NSEQ + nn) = *(const u16x8*)o;
    }
}

// ---------------- flash attention: 32x32 swapped + LDS fragment staging ----
// Best build's kernel: double buffer, STAGE -> vmcnt(4) -> barrier ->
// [QK0;QK1][SM0;SM1][PV0;PV1] -> barrier, split-stream max-tracking,
// flash-merge at end.
__global__ __launch_bounds__(256, 2) void attn_kernel(
    const unsigned short* __restrict__ Qp,   // [4096][1024], pre-scaled
    const unsigned short* __restrict__ Kh,   // [32][2048][64]
    const unsigned short* __restrict__ Vt,   // [32][64][2048]
    unsigned short* __restrict__ AO) {       // [4096][1024]
    __shared__ __align__(16) unsigned short Ks[2][4096];  // 8 frags x 512 elem
    __shared__ __align__(16) unsigned short Vs[2][4096];

    const int tid = threadIdx.x, lane = tid & 63, wid = tid >> 6;
    const int q31 = lane & 31, hi = lane >> 5;

    // XCD swizzle: 4 consecutive bh per XCD (2 MB K+V -> L2-resident)
    int bid = blockIdx.x;
    int swz = (bid & 7) * 64 + (bid >> 3);
    const int bh = swz >> 4, b = bh >> 4, h = bh & 15;
    const int qbase = ((swz & 15) * 4 + wid) * 32;

    const unsigned short* Kt = Kh + (size_t)bh * (NSEQ * HDIM);
    const unsigned short* Vb = Vt + (size_t)bh * (HDIM * NSEQ);

    // Q fragments (B-operand): lane q-col = q31, k = 16t + 8hi + e
    bf16x8 qf[4];
    {
        const unsigned short* qp =
            Qp + (size_t)(b * NSEQ + qbase + q31) * DDIM + h * HDIM + hi * 8;
#pragma unroll
        for (int t = 0; t < 4; ++t) qf[t] = *(const bf16x8*)(qp + t * 16);
    }

    // staging source offsets (fragment-order permutation), per-lane constants.
    const size_t koff0 = (size_t)q31 * HDIM + (wid & 3) * 16 + hi * 8;
    const size_t koff1 = koff0 + 32 * HDIM;
    const size_t voff0 =
        (size_t)q31 * NSEQ + ((wid >> 1) & 1) * 32 + (wid & 1) * 16 + hi * 8;
    const size_t voff1 = voff0 + (size_t)32 * NSEQ;
    const int lb0 = wid * 512, lb1 = wid * 512 + 2048;

    auto STAGE = [&](int buf, int kv0) {
        const unsigned short* kbase = Kt + (size_t)kv0 * HDIM;
        __builtin_amdgcn_global_load_lds((gq_t*)(kbase + koff0),
                                         (lq_t*)(&Ks[buf][lb0]), 16, 0, 0);
        __builtin_amdgcn_global_load_lds((gq_t*)(kbase + koff1),
                                         (lq_t*)(&Ks[buf][lb1]), 16, 0, 0);
        const unsigned short* vbase = Vb + kv0;
        __builtin_amdgcn_global_load_lds((gq_t*)(vbase + voff0),
                                         (lq_t*)(&Vs[buf][lb0]), 16, 0, 0);
        __builtin_amdgcn_global_load_lds((gq_t*)(vbase + voff1),
                                         (lq_t*)(&Vs[buf][lb1]), 16, 0, 0);
    };

    // two independent streams (even/odd half-tiles)
    f32x16 oA0, oB0, oA1, oB1;
#pragma unroll
    for (int i = 0; i < 16; ++i) {
        oA0[i] = 0.f; oB0[i] = 0.f; oA1[i] = 0.f; oB1[i] = 0.f;
    }
    float m0 = -3.0e38f, l0 = 0.f, m1 = -3.0e38f, l1 = 0.f;

    union PB { unsigned u[4]; bf16x8 v; };

    // phase 1: S^T = K^T-tile x Q (4 MFMA), per half-tile s
    auto QK = [&](int cur, int s) -> f32x16 {
        const unsigned short* kf = &Ks[cur][s * 2048 + lane * 8];
        f32x16 st;
#pragma unroll
        for (int i = 0; i < 16; ++i) st[i] = 0.f;
#pragma unroll
        for (int t = 0; t < 4; ++t)
            st = __builtin_amdgcn_mfma_f32_32x32x16_bf16(
                *(const bf16x8*)(kf + t * 512), qf[t], st, 0, 0, 0);
        return st;
    };

    // phase 2: online softmax on one stream -> packed P fragments
    auto SM = [&](const f32x16& st, float& m, float& l, f32x16& oA, f32x16& oB,
                  PB& P0, PB& P1) {
        float m8[8], m4[4];
#pragma unroll
        for (int j = 0; j < 8; ++j) m8[j] = fmaxf(st[2 * j], st[2 * j + 1]);
#pragma unroll
        for (int j = 0; j < 4; ++j) m4[j] = fmaxf(m8[2 * j], m8[2 * j + 1]);
        float pm = fmaxf(fmaxf(m4[0], m4[1]), fmaxf(m4[2], m4[3]));
        pm = fmaxf(pm, __shfl_xor(pm, 32, 64));

        // defer-max (T13): rescale only when max grew past THR=8 (log2 domain)
        if (__any(pm - m > 8.0f)) {
            float mn = fmaxf(m, pm);
            float al = exp2_fast(m - mn);
            m = mn;
            l *= al;
#pragma unroll
            for (int i = 0; i < 16; ++i) { oA[i] *= al; oB[i] *= al; }
        }

        float p[16];
#pragma unroll
        for (int i = 0; i < 16; ++i) p[i] = exp2_fast(st[i] - m);
        float s8[8], s4[4];
#pragma unroll
        for (int j = 0; j < 8; ++j) s8[j] = p[2 * j] + p[2 * j + 1];
#pragma unroll
        for (int j = 0; j < 4; ++j) s4[j] = s8[2 * j] + s8[2 * j + 1];
        float rs = (s4[0] + s4[1]) + (s4[2] + s4[3]);
        rs += __shfl_xor(rs, 32, 64);
        l += rs;

        unsigned w0 = cvtpk_bf16(p[0], p[1]), w1 = cvtpk_bf16(p[2], p[3]);
        unsigned w2 = cvtpk_bf16(p[4], p[5]), w3 = cvtpk_bf16(p[6], p[7]);
        unsigned w4 = cvtpk_bf16(p[8], p[9]), w5 = cvtpk_bf16(p[10], p[11]);
        unsigned w6 = cvtpk_bf16(p[12], p[13]), w7 = cvtpk_bf16(p[14], p[15]);
        PSWAP(w0, w2); PSWAP(w1, w3); PSWAP(w4, w6); PSWAP(w5, w7);
        P0.u[0] = w0; P0.u[1] = w1; P0.u[2] = w2; P0.u[3] = w3;  // kv 8hi+0..7
        P1.u[0] = w4; P1.u[1] = w5; P1.u[2] = w6; P1.u[3] = w7;  // kv 16+8hi+..
    };

    // phase 3: O^T += V^T-tile x P^T (4 MFMA)
    auto PV = [&](int cur, int s, const PB& P0, const PB& P1, f32x16& oA,
                  f32x16& oB) {
        const unsigned short* vf0 = &Vs[cur][s * 1024 + lane * 8];          // dh=0
        const unsigned short* vf1 = &Vs[cur][2048 + s * 1024 + lane * 8];   // dh=1
        oA = __builtin_amdgcn_mfma_f32_32x32x16_bf16(
            *(const bf16x8*)(vf0), P0.v, oA, 0, 0, 0);
        oA = __builtin_amdgcn_mfma_f32_32x32x16_bf16(
            *(const bf16x8*)(vf0 + 512), P1.v, oA, 0, 0, 0);
        oB = __builtin_amdgcn_mfma_f32_32x32x16_bf16(
            *(const bf16x8*)(vf1), P0.v, oB, 0, 0, 0);
        oB = __builtin_amdgcn_mfma_f32_32x32x16_bf16(
            *(const bf16x8*)(vf1 + 512), P1.v, oB, 0, 0, 0);
    };

    STAGE(0, 0);
    int cur = 0;
    for (int it = 0; it < 32; ++it) {
        STAGE(cur ^ 1, ((it + 1) & 31) * 64);  // prefetch next (last wraps, unused)
        asm volatile("s_waitcnt vmcnt(4)" ::: "memory");  // cur's 4 loads done
        __builtin_amdgcn_s_barrier();
        __builtin_amdgcn_sched_barrier(0);
        // one scheduling region: two independent chains per phase
        __builtin_amdgcn_s_setprio(1);
        f32x16 st0 = QK(cur, 0);
        f32x16 st1 = QK(cur, 1);
        __builtin_amdgcn_s_setprio(0);
        PB P00, P01, P10, P11;
        SM(st0, m0, l0, oA0, oB0, P00, P01);
        SM(st1, m1, l1, oA1, oB1, P10, P11);
        __builtin_amdgcn_s_setprio(1);
        PV(cur, 0, P00, P01, oA0, oB0);
        PV(cur, 1, P10, P11, oA1, oB1);
        __builtin_amdgcn_s_setprio(0);
        __builtin_amdgcn_sched_barrier(0);
        asm volatile("" ::: "memory");
        __builtin_amdgcn_s_barrier();  // all waves done reading cur
        cur ^= 1;
    }

    // merge streams + epilogue: lane q holds O^T[d][q], d=(r&3)+8*(r>>2)+4*hi
    float mt = fmaxf(m0, m1);
    float a0 = exp2_fast(m0 - mt), a1 = exp2_fast(m1 - mt);
    float inv = 1.0f / (l0 * a0 + l1 * a1);
    unsigned short* op = AO + (size_t)(b * NSEQ + qbase + q31) * DDIM + h * HDIM;
#pragma unroll
    for (int r2 = 0; r2 < 16; ++r2) {
        int d = (r2 & 3) + 8 * (r2 >> 2) + 4 * hi;
        op[d] = f2bf((oA0[r2] * a0 + oA1[r2] * a1) * inv);
        op[d + 32] = f2bf((oB0[r2] * a0 + oB1[r2] * a1) * inv);
    }
}

// ---------------- host launch ----------------
extern "C" void kernel_launch(void* const* d_in, const int* in_sizes, int n_in,
                              void* d_out, int out_size, void* d_ws, size_t ws_size,
                              hipStream_t stream) {
    const float* q = (const float*)d_in[0];
    const float* k = (const float*)d_in[1];
    const float* v = (const float*)d_in[2];
    const float* Wq = (const float*)d_in[3];
    const float* bq = (const float*)d_in[4];
    const float* Wk = (const float*)d_in[5];
    const float* bk = (const float*)d_in[6];
    const float* Wv = (const float*)d_in[7];
    const float* bv = (const float*)d_in[8];
    const float* Wo = (const float*)d_in[9];
    const float* bo = (const float*)d_in[10];
    float* out = (float*)d_out;

    unsigned short* ws = (unsigned short*)d_ws;
    const size_t TOKD = (size_t)NTOK * DDIM;  // 4,194,304
    const size_t WD = (size_t)DDIM * DDIM;    // 1,048,576
    unsigned short* qb = ws;
    unsigned short* kb = qb + TOKD;
    unsigned short* vb = kb + TOKD;
    unsigned short* Wqb = vb + TOKD;
    unsigned short* Wkb = Wqb + WD;
    unsigned short* Wvb = Wkb + WD;
    unsigned short* Wob = Wvb + WD;
    unsigned short* Qp = Wob + WD;
    unsigned short* Kp = Qp + TOKD;   // head-major K
    unsigned short* Vp = Kp + TOKD;   // token-major V
    unsigned short* AOp = Vp + TOKD;
    unsigned short* Vtb = qb;  // reuse: qb dead after gemm_qkv; V^T lives here

    const int tok8 = (int)(TOKD / 8);  // 524288
    const int w8 = (int)(WD / 8);      // 131072
    cvt_all_kernel<<<dim3(tok8 / 256, 1, 7), 256, 0, stream>>>(
        q, k, v, Wq, Wk, Wv, Wo, qb, kb, vb, Wqb, Wkb, Wvb, Wob, tok8, w8);
    gemm_qkv_kernel<<<dim3(8, 32, 3), 256, 0, stream>>>(qb, kb, vb, Wqb, Wkb, Wvb,
                                                        bq, bk, bv, Qp, Kp, Vp);
    vtrans_kernel<<<dim3(32, 32), 256, 0, stream>>>(Vp, Vtb);
    attn_kernel<<<512, 256, 0, stream>>>(Qp, Kp, Vtb, AOp);
    gemm_out_kernel<<<dim3(8, 32), 256, 0, stream>>>(AOp, Wob, bo, out);
}

// Round 20
// 134.396 us; speedup vs baseline: 1.1306x; 1.0679x over previous
//
#include <hip/hip_runtime.h>
#include <hip/hip_bf16.h>
#include <cstdint>
#include <cstddef>

#define DDIM 1024
#define NHEADS 16
#define HDIM 64
#define NSEQ 2048
#define NTOK 4096
#define QSCALE 0.18033688011112042f  // 0.125 * log2(e): folded into Q projection

typedef float f32x4 __attribute__((ext_vector_type(4)));
typedef float f32x16 __attribute__((ext_vector_type(16)));
typedef __bf16 bf16x8 __attribute__((ext_vector_type(8)));
typedef unsigned short u16x8 __attribute__((ext_vector_type(8)));

typedef __attribute__((address_space(1))) const unsigned int gq_t;
typedef __attribute__((address_space(3))) unsigned int lq_t;

__device__ __forceinline__ unsigned short f2bf(float f) {
    union { float f; unsigned int u; } v; v.f = f;
    unsigned int u = v.u;
    u += 0x7FFFu + ((u >> 16) & 1u);
    return (unsigned short)(u >> 16);
}

// raw v_exp_f32 = 2^x ; s_nop covers the trans-op hazard for the consumer
__device__ __forceinline__ float exp2_fast(float x) {
    float r;
    asm("v_exp_f32 %0, %1\n\ts_nop 0" : "=v"(r) : "v"(x));
    return r;
}

__device__ __forceinline__ unsigned cvtpk_bf16(float lo, float hi) {
    unsigned r;
    asm("v_cvt_pk_bf16_f32 %0, %1, %2" : "=v"(r) : "v"(lo), "v"(hi));
    return r;
}

#define PSWAP(a, b) asm("v_permlane32_swap_b32 %0, %1" : "+v"(a), "+v"(b))

// ---------------- fp32 -> bf16 converts (ONE launch, 7 z-slices) ----------
__global__ __launch_bounds__(256) void cvt_all_kernel(
    const float* __restrict__ a0, const float* __restrict__ a1,
    const float* __restrict__ a2, const float* __restrict__ a3,
    const float* __restrict__ a4, const float* __restrict__ a5,
    const float* __restrict__ a6, unsigned short* __restrict__ d0,
    unsigned short* __restrict__ d1, unsigned short* __restrict__ d2,
    unsigned short* __restrict__ d3, unsigned short* __restrict__ d4,
    unsigned short* __restrict__ d5, unsigned short* __restrict__ d6,
    int tok8, int w8) {
    int z = blockIdx.z;
    const float* s = z == 0 ? a0 : z == 1 ? a1 : z == 2 ? a2 : z == 3 ? a3
                     : z == 4 ? a4 : z == 5 ? a5 : a6;
    unsigned short* d = z == 0 ? d0 : z == 1 ? d1 : z == 2 ? d2 : z == 3 ? d3
                        : z == 4 ? d4 : z == 5 ? d5 : d6;
    int n8 = (z < 3) ? tok8 : w8;
    int i = blockIdx.x * 256 + threadIdx.x;
    if (i >= n8) return;
    const float4* s4 = (const float4*)s + (size_t)i * 2;
    float4 a = s4[0], b = s4[1];
    unsigned short o[8] __attribute__((aligned(16)));
    o[0] = f2bf(a.x); o[1] = f2bf(a.y); o[2] = f2bf(a.z); o[3] = f2bf(a.w);
    o[4] = f2bf(b.x); o[5] = f2bf(b.y); o[6] = f2bf(b.z); o[7] = f2bf(b.w);
    *(u16x8*)(d + (size_t)i * 8) = *(const u16x8*)o;
}

// ---------------- GEMM: C[m,n] = sum_k A[m,k]*W[n,k] + bias[n] ----------------
// Best build (143.3 us) + vtrans FUSED into mode-2 epilogue: 128x128 tile,
// BK=32, 4 waves, global_load_lds staging, 2-barrier loop, XCD swizzle.
// mode 0: Q -> bf16 scaled; 1: K head-major [32][2048][64];
// mode 2: V^T head-major [32][64][2048] (4 consecutive n -> one 8B store);
// mode 3: f32 out.
__device__ __forceinline__ void gemm_body(const unsigned short* __restrict__ A,
                                          const unsigned short* __restrict__ W,
                                          const float* __restrict__ bias,
                                          int mode, void* __restrict__ Cout) {
    __shared__ __align__(16) unsigned short As[128 * 32];
    __shared__ __align__(16) unsigned short Bs[128 * 32];
    const int tid = threadIdx.x, lane = tid & 63, wid = tid >> 6;
    const int r = lane & 15, g = lane >> 4;
    // XCD swizzle: hardware f = y*8+x round-robins across 8 XCDs; remap so
    // each XCD gets 32 contiguous blocks = 4 m-panels x 8 n-panels.
    const int f = blockIdx.y * 8 + blockIdx.x;     // 0..255 per z
    const int swz = (f & 7) * 32 + (f >> 3);
    const int mbase = (swz >> 3) * 128;
    const int nbase = (swz & 7) * 128;
    const int wm = (wid >> 1) * 64, wn = (wid & 1) * 64;

    f32x4 zero = {0.f, 0.f, 0.f, 0.f};
    f32x4 acc[4][4];
#pragma unroll
    for (int mi = 0; mi < 4; ++mi)
#pragma unroll
        for (int ni = 0; ni < 4; ++ni) acc[mi][ni] = zero;

    for (int kt = 0; kt < 1024; kt += 32) {
        __syncthreads();
#pragma unroll
        for (int j = 0; j < 2; ++j) {
            int ub = wid * 64 + j * 256;  // wave-uniform 16B-unit base
            int uu = ub + lane;
            const unsigned short* ga =
                A + (size_t)(mbase + (uu >> 2)) * 1024 + kt + (uu & 3) * 8;
            __builtin_amdgcn_global_load_lds((gq_t*)ga, (lq_t*)(As + ub * 8), 16, 0, 0);
            const unsigned short* gb =
                W + (size_t)(nbase + (uu >> 2)) * 1024 + kt + (uu & 3) * 8;
            __builtin_amdgcn_global_load_lds((gq_t*)gb, (lq_t*)(Bs + ub * 8), 16, 0, 0);
        }
        __syncthreads();
        bf16x8 af[4], bf[4];
#pragma unroll
        for (int mi = 0; mi < 4; ++mi)
            af[mi] = *(const bf16x8*)(As + (wm + mi * 16 + r) * 32 + g * 8);
#pragma unroll
        for (int ni = 0; ni < 4; ++ni)
            bf[ni] = *(const bf16x8*)(Bs + (wn + ni * 16 + r) * 32 + g * 8);
#pragma unroll
        for (int mi = 0; mi < 4; ++mi)
#pragma unroll
            for (int ni = 0; ni < 4; ++ni)
                acc[mi][ni] = __builtin_amdgcn_mfma_f32_16x16x32_bf16(
                    af[mi], bf[ni], acc[mi][ni], 0, 0, 0);
    }
    // epilogue: C row = (lane>>4)*4 + reg, col = lane&15
#pragma unroll
    for (int mi = 0; mi < 4; ++mi) {
#pragma unroll
        for (int ni = 0; ni < 4; ++ni) {
            int c = nbase + wn + ni * 16 + r;
            float bv = bias[c];
            float v4[4];
#pragma unroll
            for (int rr = 0; rr < 4; ++rr) v4[rr] = acc[mi][ni][rr] + bv;
            int m0 = mbase + wm + mi * 16 + g * 4;
            if (mode == 0) {
#pragma unroll
                for (int rr = 0; rr < 4; ++rr)
                    ((unsigned short*)Cout)[(size_t)(m0 + rr) * 1024 + c] =
                        f2bf(v4[rr] * QSCALE);
            } else if (mode == 1) {
                // K head-major [bh][n][d]
                size_t base = ((size_t)((m0 >> 11) * 16 + (c >> 6)) * 2048 +
                               (size_t)(m0 & 2047)) * 64 + (c & 63);
#pragma unroll
                for (int rr = 0; rr < 4; ++rr)
                    ((unsigned short*)Cout)[base + (size_t)rr * 64] = f2bf(v4[rr]);
            } else if (mode == 2) {
                // V^T [bh][d][n]: 4 consecutive n (m0 4-aligned) -> 8B store
                unsigned short o4[4] __attribute__((aligned(8)));
#pragma unroll
                for (int rr = 0; rr < 4; ++rr) o4[rr] = f2bf(v4[rr]);
                size_t base = ((size_t)((m0 >> 11) * 16 + (c >> 6)) * 64 +
                               (c & 63)) * 2048 + (size_t)(m0 & 2047);
                *(ushort4*)((unsigned short*)Cout + base) = *(const ushort4*)o4;
            } else {
#pragma unroll
                for (int rr = 0; rr < 4; ++rr)
                    ((float*)Cout)[(size_t)(m0 + rr) * 1024 + c] = v4[rr];
            }
        }
    }
}

__global__ __launch_bounds__(256) void gemm_qkv_kernel(
    const unsigned short* __restrict__ qb, const unsigned short* __restrict__ kb,
    const unsigned short* __restrict__ vb, const unsigned short* __restrict__ Wq,
    const unsigned short* __restrict__ Wk, const unsigned short* __restrict__ Wv,
    const float* __restrict__ bq, const float* __restrict__ bk,
    const float* __restrict__ bv, unsigned short* __restrict__ Qp,
    unsigned short* __restrict__ Kp, unsigned short* __restrict__ Vp) {
    int z = blockIdx.z;
    const unsigned short* A = (z == 0) ? qb : (z == 1) ? kb : vb;
    const unsigned short* W = (z == 0) ? Wq : (z == 1) ? Wk : Wv;
    const float* bias = (z == 0) ? bq : (z == 1) ? bk : bv;
    unsigned short* C = (z == 0) ? Qp : (z == 1) ? Kp : Vp;
    gemm_body(A, W, bias, z, C);
}

__global__ __launch_bounds__(256) void gemm_out_kernel(
    const unsigned short* __restrict__ AO, const unsigned short* __restrict__ Wo,
    const float* __restrict__ bo, float* __restrict__ out) {
    gemm_body(AO, Wo, bo, 3, out);
}

// ---------------- flash attention: 32x32 swapped + LDS fragment staging ----
// Best build's kernel, unchanged: double buffer, STAGE -> vmcnt(4) ->
// barrier -> [QK0;QK1][SM0;SM1][PV0;PV1] -> barrier, split-stream
// max-tracking, flash-merge at end. V^T now comes straight from gemm_qkv.
__global__ __launch_bounds__(256, 2) void attn_kernel(
    const unsigned short* __restrict__ Qp,   // [4096][1024], pre-scaled
    const unsigned short* __restrict__ Kh,   // [32][2048][64]
    const unsigned short* __restrict__ Vt,   // [32][64][2048]
    unsigned short* __restrict__ AO) {       // [4096][1024]
    __shared__ __align__(16) unsigned short Ks[2][4096];  // 8 frags x 512 elem
    __shared__ __align__(16) unsigned short Vs[2][4096];

    const int tid = threadIdx.x, lane = tid & 63, wid = tid >> 6;
    const int q31 = lane & 31, hi = lane >> 5;

    // XCD swizzle: 4 consecutive bh per XCD (2 MB K+V -> L2-resident)
    int bid = blockIdx.x;
    int swz = (bid & 7) * 64 + (bid >> 3);
    const int bh = swz >> 4, b = bh >> 4, h = bh & 15;
    const int qbase = ((swz & 15) * 4 + wid) * 32;

    const unsigned short* Kt = Kh + (size_t)bh * (NSEQ * HDIM);
    const unsigned short* Vb = Vt + (size_t)bh * (HDIM * NSEQ);

    // Q fragments (B-operand): lane q-col = q31, k = 16t + 8hi + e
    bf16x8 qf[4];
    {
        const unsigned short* qp =
            Qp + (size_t)(b * NSEQ + qbase + q31) * DDIM + h * HDIM + hi * 8;
#pragma unroll
        for (int t = 0; t < 4; ++t) qf[t] = *(const bf16x8*)(qp + t * 16);
    }

    // staging source offsets (fragment-order permutation), per-lane constants.
    const size_t koff0 = (size_t)q31 * HDIM + (wid & 3) * 16 + hi * 8;
    const size_t koff1 = koff0 + 32 * HDIM;
    const size_t voff0 =
        (size_t)q31 * NSEQ + ((wid >> 1) & 1) * 32 + (wid & 1) * 16 + hi * 8;
    const size_t voff1 = voff0 + (size_t)32 * NSEQ;
    const int lb0 = wid * 512, lb1 = wid * 512 + 2048;

    auto STAGE = [&](int buf, int kv0) {
        const unsigned short* kbase = Kt + (size_t)kv0 * HDIM;
        __builtin_amdgcn_global_load_lds((gq_t*)(kbase + koff0),
                                         (lq_t*)(&Ks[buf][lb0]), 16, 0, 0);
        __builtin_amdgcn_global_load_lds((gq_t*)(kbase + koff1),
                                         (lq_t*)(&Ks[buf][lb1]), 16, 0, 0);
        const unsigned short* vbase = Vb + kv0;
        __builtin_amdgcn_global_load_lds((gq_t*)(vbase + voff0),
                                         (lq_t*)(&Vs[buf][lb0]), 16, 0, 0);
        __builtin_amdgcn_global_load_lds((gq_t*)(vbase + voff1),
                                         (lq_t*)(&Vs[buf][lb1]), 16, 0, 0);
    };

    // two independent streams (even/odd half-tiles)
    f32x16 oA0, oB0, oA1, oB1;
#pragma unroll
    for (int i = 0; i < 16; ++i) {
        oA0[i] = 0.f; oB0[i] = 0.f; oA1[i] = 0.f; oB1[i] = 0.f;
    }
    float m0 = -3.0e38f, l0 = 0.f, m1 = -3.0e38f, l1 = 0.f;

    union PB { unsigned u[4]; bf16x8 v; };

    // phase 1: S^T = K^T-tile x Q (4 MFMA), per half-tile s
    auto QK = [&](int cur, int s) -> f32x16 {
        const unsigned short* kf = &Ks[cur][s * 2048 + lane * 8];
        f32x16 st;
#pragma unroll
        for (int i = 0; i < 16; ++i) st[i] = 0.f;
#pragma unroll
        for (int t = 0; t < 4; ++t)
            st = __builtin_amdgcn_mfma_f32_32x32x16_bf16(
                *(const bf16x8*)(kf + t * 512), qf[t], st, 0, 0, 0);
        return st;
    };

    // phase 2: online softmax on one stream -> packed P fragments
    auto SM = [&](const f32x16& st, float& m, float& l, f32x16& oA, f32x16& oB,
                  PB& P0, PB& P1) {
        float m8[8], m4[4];
#pragma unroll
        for (int j = 0; j < 8; ++j) m8[j] = fmaxf(st[2 * j], st[2 * j + 1]);
#pragma unroll
        for (int j = 0; j < 4; ++j) m4[j] = fmaxf(m8[2 * j], m8[2 * j + 1]);
        float pm = fmaxf(fmaxf(m4[0], m4[1]), fmaxf(m4[2], m4[3]));
        pm = fmaxf(pm, __shfl_xor(pm, 32, 64));

        // defer-max (T13): rescale only when max grew past THR=8 (log2 domain)
        if (__any(pm - m > 8.0f)) {
            float mn = fmaxf(m, pm);
            float al = exp2_fast(m - mn);
            m = mn;
            l *= al;
#pragma unroll
            for (int i = 0; i < 16; ++i) { oA[i] *= al; oB[i] *= al; }
        }

        float p[16];
#pragma unroll
        for (int i = 0; i < 16; ++i) p[i] = exp2_fast(st[i] - m);
        float s8[8], s4[4];
#pragma unroll
        for (int j = 0; j < 8; ++j) s8[j] = p[2 * j] + p[2 * j + 1];
#pragma unroll
        for (int j = 0; j < 4; ++j) s4[j] = s8[2 * j] + s8[2 * j + 1];
        float rs = (s4[0] + s4[1]) + (s4[2] + s4[3]);
        rs += __shfl_xor(rs, 32, 64);
        l += rs;

        unsigned w0 = cvtpk_bf16(p[0], p[1]), w1 = cvtpk_bf16(p[2], p[3]);
        unsigned w2 = cvtpk_bf16(p[4], p[5]), w3 = cvtpk_bf16(p[6], p[7]);
        unsigned w4 = cvtpk_bf16(p[8], p[9]), w5 = cvtpk_bf16(p[10], p[11]);
        unsigned w6 = cvtpk_bf16(p[12], p[13]), w7 = cvtpk_bf16(p[14], p[15]);
        PSWAP(w0, w2); PSWAP(w1, w3); PSWAP(w4, w6); PSWAP(w5, w7);
        P0.u[0] = w0; P0.u[1] = w1; P0.u[2] = w2; P0.u[3] = w3;  // kv 8hi+0..7
        P1.u[0] = w4; P1.u[1] = w5; P1.u[2] = w6; P1.u[3] = w7;  // kv 16+8hi+..
    };

    // phase 3: O^T += V^T-tile x P^T (4 MFMA)
    auto PV = [&](int cur, int s, const PB& P0, const PB& P1, f32x16& oA,
                  f32x16& oB) {
        const unsigned short* vf0 = &Vs[cur][s * 1024 + lane * 8];          // dh=0
        const unsigned short* vf1 = &Vs[cur][2048 + s * 1024 + lane * 8];   // dh=1
        oA = __builtin_amdgcn_mfma_f32_32x32x16_bf16(
            *(const bf16x8*)(vf0), P0.v, oA, 0, 0, 0);
        oA = __builtin_amdgcn_mfma_f32_32x32x16_bf16(
            *(const bf16x8*)(vf0 + 512), P1.v, oA, 0, 0, 0);
        oB = __builtin_amdgcn_mfma_f32_32x32x16_bf16(
            *(const bf16x8*)(vf1), P0.v, oB, 0, 0, 0);
        oB = __builtin_amdgcn_mfma_f32_32x32x16_bf16(
            *(const bf16x8*)(vf1 + 512), P1.v, oB, 0, 0, 0);
    };

    STAGE(0, 0);
    int cur = 0;
    for (int it = 0; it < 32; ++it) {
        STAGE(cur ^ 1, ((it + 1) & 31) * 64);  // prefetch next (last wraps, unused)
        asm volatile("s_waitcnt vmcnt(4)" ::: "memory");  // cur's 4 loads done
        __builtin_amdgcn_s_barrier();
        __builtin_amdgcn_sched_barrier(0);
        // one scheduling region: two independent chains per phase
        __builtin_amdgcn_s_setprio(1);
        f32x16 st0 = QK(cur, 0);
        f32x16 st1 = QK(cur, 1);
        __builtin_amdgcn_s_setprio(0);
        PB P00, P01, P10, P11;
        SM(st0, m0, l0, oA0, oB0, P00, P01);
        SM(st1, m1, l1, oA1, oB1, P10, P11);
        __builtin_amdgcn_s_setprio(1);
        PV(cur, 0, P00, P01, oA0, oB0);
        PV(cur, 1, P10, P11, oA1, oB1);
        __builtin_amdgcn_s_setprio(0);
        __builtin_amdgcn_sched_barrier(0);
        asm volatile("" ::: "memory");
        __builtin_amdgcn_s_barrier();  // all waves done reading cur
        cur ^= 1;
    }

    // merge streams + epilogue: lane q holds O^T[d][q], d=(r&3)+8*(r>>2)+4*hi
    float mt = fmaxf(m0, m1);
    float a0 = exp2_fast(m0 - mt), a1 = exp2_fast(m1 - mt);
    float inv = 1.0f / (l0 * a0 + l1 * a1);
    unsigned short* op = AO + (size_t)(b * NSEQ + qbase + q31) * DDIM + h * HDIM;
#pragma unroll
    for (int r2 = 0; r2 < 16; ++r2) {
        int d = (r2 & 3) + 8 * (r2 >> 2) + 4 * hi;
        op[d] = f2bf((oA0[r2] * a0 + oA1[r2] * a1) * inv);
        op[d + 32] = f2bf((oB0[r2] * a0 + oB1[r2] * a1) * inv);
    }
}

// ---------------- host launch ----------------
extern "C" void kernel_launch(void* const* d_in, const int* in_sizes, int n_in,
                              void* d_out, int out_size, void* d_ws, size_t ws_size,
                              hipStream_t stream) {
    const float* q = (const float*)d_in[0];
    const float* k = (const float*)d_in[1];
    const float* v = (const float*)d_in[2];
    const float* Wq = (const float*)d_in[3];
    const float* bq = (const float*)d_in[4];
    const float* Wk = (const float*)d_in[5];
    const float* bk = (const float*)d_in[6];
    const float* Wv = (const float*)d_in[7];
    const float* bv = (const float*)d_in[8];
    const float* Wo = (const float*)d_in[9];
    const float* bo = (const float*)d_in[10];
    float* out = (float*)d_out;

    unsigned short* ws = (unsigned short*)d_ws;
    const size_t TOKD = (size_t)NTOK * DDIM;  // 4,194,304
    const size_t WD = (size_t)DDIM * DDIM;    // 1,048,576
    unsigned short* qb = ws;
    unsigned short* kb = qb + TOKD;
    unsigned short* vb = kb + TOKD;
    unsigned short* Wqb = vb + TOKD;
    unsigned short* Wkb = Wqb + WD;
    unsigned short* Wvb = Wkb + WD;
    unsigned short* Wob = Wvb + WD;
    unsigned short* Qp = Wob + WD;
    unsigned short* Kp = Qp + TOKD;   // head-major K [32][2048][64]
    unsigned short* Vp = Kp + TOKD;   // head-major V^T [32][64][2048] (fused)
    unsigned short* AOp = Vp + TOKD;

    const int tok8 = (int)(TOKD / 8);  // 524288
    const int w8 = (int)(WD / 8);      // 131072
    cvt_all_kernel<<<dim3(tok8 / 256, 1, 7), 256, 0, stream>>>(
        q, k, v, Wq, Wk, Wv, Wo, qb, kb, vb, Wqb, Wkb, Wvb, Wob, tok8, w8);
    gemm_qkv_kernel<<<dim3(8, 32, 3), 256, 0, stream>>>(qb, kb, vb, Wqb, Wkb, Wvb,
                                                        bq, bk, bv, Qp, Kp, Vp);
    attn_kernel<<<512, 256, 0, stream>>>(Qp, Kp, Vp, AOp);
    gemm_out_kernel<<<dim3(8, 32), 256, 0, stream>>>(AOp, Wob, bo, out);
}

// Round 21
// 132.898 us; speedup vs baseline: 1.1433x; 1.0113x over previous
//
#include <hip/hip_runtime.h>
#include <hip/hip_bf16.h>
#include <cstdint>
#include <cstddef>

#define DDIM 1024
#define NHEADS 16
#define HDIM 64
#define NSEQ 2048
#define NTOK 4096
#define QSCALE 0.18033688011112042f  // 0.125 * log2(e): folded into Q projection

typedef float f32x4 __attribute__((ext_vector_type(4)));
typedef float f32x16 __attribute__((ext_vector_type(16)));
typedef __bf16 bf16x8 __attribute__((ext_vector_type(8)));
typedef unsigned short u16x8 __attribute__((ext_vector_type(8)));

typedef __attribute__((address_space(1))) const unsigned int gq_t;
typedef __attribute__((address_space(3))) unsigned int lq_t;

__device__ __forceinline__ unsigned short f2bf(float f) {
    union { float f; unsigned int u; } v; v.f = f;
    unsigned int u = v.u;
    u += 0x7FFFu + ((u >> 16) & 1u);
    return (unsigned short)(u >> 16);
}

// raw v_exp_f32 = 2^x ; s_nop covers the trans-op hazard for the consumer
__device__ __forceinline__ float exp2_fast(float x) {
    float r;
    asm("v_exp_f32 %0, %1\n\ts_nop 0" : "=v"(r) : "v"(x));
    return r;
}

__device__ __forceinline__ unsigned cvtpk_bf16(float lo, float hi) {
    unsigned r;
    asm("v_cvt_pk_bf16_f32 %0, %1, %2" : "=v"(r) : "v"(lo), "v"(hi));
    return r;
}

#define PSWAP(a, b) asm("v_permlane32_swap_b32 %0, %1" : "+v"(a), "+v"(b))

// ---------------- fp32 -> bf16 convert: WEIGHTS ONLY (4 z-slices) ----------
__global__ __launch_bounds__(256) void cvt_w_kernel(
    const float* __restrict__ a0, const float* __restrict__ a1,
    const float* __restrict__ a2, const float* __restrict__ a3,
    unsigned short* __restrict__ d0, unsigned short* __restrict__ d1,
    unsigned short* __restrict__ d2, unsigned short* __restrict__ d3) {
    int z = blockIdx.z;
    const float* s = z == 0 ? a0 : z == 1 ? a1 : z == 2 ? a2 : a3;
    unsigned short* d = z == 0 ? d0 : z == 1 ? d1 : z == 2 ? d2 : d3;
    int i = blockIdx.x * 256 + threadIdx.x;
    const float4* s4 = (const float4*)s + (size_t)i * 2;
    float4 a = s4[0], b = s4[1];
    unsigned short o[8] __attribute__((aligned(16)));
    o[0] = f2bf(a.x); o[1] = f2bf(a.y); o[2] = f2bf(a.z); o[3] = f2bf(a.w);
    o[4] = f2bf(b.x); o[5] = f2bf(b.y); o[6] = f2bf(b.z); o[7] = f2bf(b.w);
    *(u16x8*)(d + (size_t)i * 8) = *(const u16x8*)o;
}

// ---------------- GEMM: C[m,n] = sum_k A[m,k]*W[n,k] + bias[n] ----------------
// Best-build structure (r20, 134.4 us): 128x128 tile, BK=32, 4 waves,
// 2-barrier loop, XCD swizzle, V^T fused into mode-2 epilogue.
// NEW: AF32 path — A read as fp32 and converted in-register during staging
// (2x float4 -> 8x f2bf -> ds_write_b128, same LDS layout); fuses the q/k/v
// cvt pass into the GEMM. B always stages via global_load_lds (bf16).
// mode 0: Q -> bf16 scaled; 1: K head-major [32][2048][64];
// mode 2: V^T head-major [32][64][2048]; mode 3: f32 out.
template <bool AF32>
__device__ __forceinline__ void gemm_body(const void* __restrict__ Ain,
                                          const unsigned short* __restrict__ W,
                                          const float* __restrict__ bias,
                                          int mode, void* __restrict__ Cout) {
    __shared__ __align__(16) unsigned short As[128 * 32];
    __shared__ __align__(16) unsigned short Bs[128 * 32];
    const int tid = threadIdx.x, lane = tid & 63, wid = tid >> 6;
    const int r = lane & 15, g = lane >> 4;
    // XCD swizzle: hardware f = y*8+x round-robins across 8 XCDs; remap so
    // each XCD gets 32 contiguous blocks = 4 m-panels x 8 n-panels.
    const int f = blockIdx.y * 8 + blockIdx.x;     // 0..255 per z
    const int swz = (f & 7) * 32 + (f >> 3);
    const int mbase = (swz >> 3) * 128;
    const int nbase = (swz & 7) * 128;
    const int wm = (wid >> 1) * 64, wn = (wid & 1) * 64;

    f32x4 zero = {0.f, 0.f, 0.f, 0.f};
    f32x4 acc[4][4];
#pragma unroll
    for (int mi = 0; mi < 4; ++mi)
#pragma unroll
        for (int ni = 0; ni < 4; ++ni) acc[mi][ni] = zero;

    for (int kt = 0; kt < 1024; kt += 32) {
        __syncthreads();
#pragma unroll
        for (int j = 0; j < 2; ++j) {
            int ub = wid * 64 + j * 256;  // wave-uniform 16B-unit base
            int uu = ub + lane;
            if (AF32) {
                // reg-stage A from fp32: same LDS layout as global_load_lds
                const float* ga = (const float*)Ain +
                                  (size_t)(mbase + (uu >> 2)) * 1024 + kt +
                                  (uu & 3) * 8;
                float4 x = *(const float4*)ga;
                float4 y = *(const float4*)(ga + 4);
                unsigned short o[8] __attribute__((aligned(16)));
                o[0] = f2bf(x.x); o[1] = f2bf(x.y);
                o[2] = f2bf(x.z); o[3] = f2bf(x.w);
                o[4] = f2bf(y.x); o[5] = f2bf(y.y);
                o[6] = f2bf(y.z); o[7] = f2bf(y.w);
                *(u16x8*)(As + (size_t)uu * 8) = *(const u16x8*)o;
            } else {
                const unsigned short* ga =
                    (const unsigned short*)Ain +
                    (size_t)(mbase + (uu >> 2)) * 1024 + kt + (uu & 3) * 8;
                __builtin_amdgcn_global_load_lds((gq_t*)ga, (lq_t*)(As + ub * 8),
                                                 16, 0, 0);
            }
            const unsigned short* gb =
                W + (size_t)(nbase + (uu >> 2)) * 1024 + kt + (uu & 3) * 8;
            __builtin_amdgcn_global_load_lds((gq_t*)gb, (lq_t*)(Bs + ub * 8), 16, 0, 0);
        }
        __syncthreads();
        bf16x8 af[4], bf[4];
#pragma unroll
        for (int mi = 0; mi < 4; ++mi)
            af[mi] = *(const bf16x8*)(As + (wm + mi * 16 + r) * 32 + g * 8);
#pragma unroll
        for (int ni = 0; ni < 4; ++ni)
            bf[ni] = *(const bf16x8*)(Bs + (wn + ni * 16 + r) * 32 + g * 8);
#pragma unroll
        for (int mi = 0; mi < 4; ++mi)
#pragma unroll
            for (int ni = 0; ni < 4; ++ni)
                acc[mi][ni] = __builtin_amdgcn_mfma_f32_16x16x32_bf16(
                    af[mi], bf[ni], acc[mi][ni], 0, 0, 0);
    }
    // epilogue: C row = (lane>>4)*4 + reg, col = lane&15
#pragma unroll
    for (int mi = 0; mi < 4; ++mi) {
#pragma unroll
        for (int ni = 0; ni < 4; ++ni) {
            int c = nbase + wn + ni * 16 + r;
            float bv = bias[c];
            float v4[4];
#pragma unroll
            for (int rr = 0; rr < 4; ++rr) v4[rr] = acc[mi][ni][rr] + bv;
            int m0 = mbase + wm + mi * 16 + g * 4;
            if (mode == 0) {
#pragma unroll
                for (int rr = 0; rr < 4; ++rr)
                    ((unsigned short*)Cout)[(size_t)(m0 + rr) * 1024 + c] =
                        f2bf(v4[rr] * QSCALE);
            } else if (mode == 1) {
                // K head-major [bh][n][d]
                size_t base = ((size_t)((m0 >> 11) * 16 + (c >> 6)) * 2048 +
                               (size_t)(m0 & 2047)) * 64 + (c & 63);
#pragma unroll
                for (int rr = 0; rr < 4; ++rr)
                    ((unsigned short*)Cout)[base + (size_t)rr * 64] = f2bf(v4[rr]);
            } else if (mode == 2) {
                // V^T [bh][d][n]: 4 consecutive n (m0 4-aligned) -> 8B store
                unsigned short o4[4] __attribute__((aligned(8)));
#pragma unroll
                for (int rr = 0; rr < 4; ++rr) o4[rr] = f2bf(v4[rr]);
                size_t base = ((size_t)((m0 >> 11) * 16 + (c >> 6)) * 64 +
                               (c & 63)) * 2048 + (size_t)(m0 & 2047);
                *(ushort4*)((unsigned short*)Cout + base) = *(const ushort4*)o4;
            } else {
#pragma unroll
                for (int rr = 0; rr < 4; ++rr)
                    ((float*)Cout)[(size_t)(m0 + rr) * 1024 + c] = v4[rr];
            }
        }
    }
}

// QKV: A = fp32 activations straight from d_in (cvt fused into staging)
__global__ __launch_bounds__(256) void gemm_qkv_kernel(
    const float* __restrict__ qf32, const float* __restrict__ kf32,
    const float* __restrict__ vf32, const unsigned short* __restrict__ Wq,
    const unsigned short* __restrict__ Wk, const unsigned short* __restrict__ Wv,
    const float* __restrict__ bq, const float* __restrict__ bk,
    const float* __restrict__ bv, unsigned short* __restrict__ Qp,
    unsigned short* __restrict__ Kp, unsigned short* __restrict__ Vp) {
    int z = blockIdx.z;
    const float* A = (z == 0) ? qf32 : (z == 1) ? kf32 : vf32;
    const unsigned short* W = (z == 0) ? Wq : (z == 1) ? Wk : Wv;
    const float* bias = (z == 0) ? bq : (z == 1) ? bk : bv;
    unsigned short* C = (z == 0) ? Qp : (z == 1) ? Kp : Vp;
    gemm_body<true>(A, W, bias, z, C);
}

__global__ __launch_bounds__(256) void gemm_out_kernel(
    const unsigned short* __restrict__ AO, const unsigned short* __restrict__ Wo,
    const float* __restrict__ bo, float* __restrict__ out) {
    gemm_body<false>(AO, Wo, bo, 3, out);
}

// ---------------- flash attention: 32x32 swapped + LDS fragment staging ----
// Best build's kernel, unchanged: double buffer, STAGE -> vmcnt(4) ->
// barrier -> [QK0;QK1][SM0;SM1][PV0;PV1] -> barrier, split-stream
// max-tracking, flash-merge at end.
__global__ __launch_bounds__(256, 2) void attn_kernel(
    const unsigned short* __restrict__ Qp,   // [4096][1024], pre-scaled
    const unsigned short* __restrict__ Kh,   // [32][2048][64]
    const unsigned short* __restrict__ Vt,   // [32][64][2048]
    unsigned short* __restrict__ AO) {       // [4096][1024]
    __shared__ __align__(16) unsigned short Ks[2][4096];  // 8 frags x 512 elem
    __shared__ __align__(16) unsigned short Vs[2][4096];

    const int tid = threadIdx.x, lane = tid & 63, wid = tid >> 6;
    const int q31 = lane & 31, hi = lane >> 5;

    // XCD swizzle: 4 consecutive bh per XCD (2 MB K+V -> L2-resident)
    int bid = blockIdx.x;
    int swz = (bid & 7) * 64 + (bid >> 3);
    const int bh = swz >> 4, b = bh >> 4, h = bh & 15;
    const int qbase = ((swz & 15) * 4 + wid) * 32;

    const unsigned short* Kt = Kh + (size_t)bh * (NSEQ * HDIM);
    const unsigned short* Vb = Vt + (size_t)bh * (HDIM * NSEQ);

    // Q fragments (B-operand): lane q-col = q31, k = 16t + 8hi + e
    bf16x8 qf[4];
    {
        const unsigned short* qp =
            Qp + (size_t)(b * NSEQ + qbase + q31) * DDIM + h * HDIM + hi * 8;
#pragma unroll
        for (int t = 0; t < 4; ++t) qf[t] = *(const bf16x8*)(qp + t * 16);
    }

    // staging source offsets (fragment-order permutation), per-lane constants.
    const size_t koff0 = (size_t)q31 * HDIM + (wid & 3) * 16 + hi * 8;
    const size_t koff1 = koff0 + 32 * HDIM;
    const size_t voff0 =
        (size_t)q31 * NSEQ + ((wid >> 1) & 1) * 32 + (wid & 1) * 16 + hi * 8;
    const size_t voff1 = voff0 + (size_t)32 * NSEQ;
    const int lb0 = wid * 512, lb1 = wid * 512 + 2048;

    auto STAGE = [&](int buf, int kv0) {
        const unsigned short* kbase = Kt + (size_t)kv0 * HDIM;
        __builtin_amdgcn_global_load_lds((gq_t*)(kbase + koff0),
                                         (lq_t*)(&Ks[buf][lb0]), 16, 0, 0);
        __builtin_amdgcn_global_load_lds((gq_t*)(kbase + koff1),
                                         (lq_t*)(&Ks[buf][lb1]), 16, 0, 0);
        const unsigned short* vbase = Vb + kv0;
        __builtin_amdgcn_global_load_lds((gq_t*)(vbase + voff0),
                                         (lq_t*)(&Vs[buf][lb0]), 16, 0, 0);
        __builtin_amdgcn_global_load_lds((gq_t*)(vbase + voff1),
                                         (lq_t*)(&Vs[buf][lb1]), 16, 0, 0);
    };

    // two independent streams (even/odd half-tiles)
    f32x16 oA0, oB0, oA1, oB1;
#pragma unroll
    for (int i = 0; i < 16; ++i) {
        oA0[i] = 0.f; oB0[i] = 0.f; oA1[i] = 0.f; oB1[i] = 0.f;
    }
    float m0 = -3.0e38f, l0 = 0.f, m1 = -3.0e38f, l1 = 0.f;

    union PB { unsigned u[4]; bf16x8 v; };

    // phase 1: S^T = K^T-tile x Q (4 MFMA), per half-tile s
    auto QK = [&](int cur, int s) -> f32x16 {
        const unsigned short* kf = &Ks[cur][s * 2048 + lane * 8];
        f32x16 st;
#pragma unroll
        for (int i = 0; i < 16; ++i) st[i] = 0.f;
#pragma unroll
        for (int t = 0; t < 4; ++t)
            st = __builtin_amdgcn_mfma_f32_32x32x16_bf16(
                *(const bf16x8*)(kf + t * 512), qf[t], st, 0, 0, 0);
        return st;
    };

    // phase 2: online softmax on one stream -> packed P fragments
    auto SM = [&](const f32x16& st, float& m, float& l, f32x16& oA, f32x16& oB,
                  PB& P0, PB& P1) {
        float m8[8], m4[4];
#pragma unroll
        for (int j = 0; j < 8; ++j) m8[j] = fmaxf(st[2 * j], st[2 * j + 1]);
#pragma unroll
        for (int j = 0; j < 4; ++j) m4[j] = fmaxf(m8[2 * j], m8[2 * j + 1]);
        float pm = fmaxf(fmaxf(m4[0], m4[1]), fmaxf(m4[2], m4[3]));
        pm = fmaxf(pm, __shfl_xor(pm, 32, 64));

        // defer-max (T13): rescale only when max grew past THR=8 (log2 domain)
        if (__any(pm - m > 8.0f)) {
            float mn = fmaxf(m, pm);
            float al = exp2_fast(m - mn);
            m = mn;
            l *= al;
#pragma unroll
            for (int i = 0; i < 16; ++i) { oA[i] *= al; oB[i] *= al; }
        }

        float p[16];
#pragma unroll
        for (int i = 0; i < 16; ++i) p[i] = exp2_fast(st[i] - m);
        float s8[8], s4[4];
#pragma unroll
        for (int j = 0; j < 8; ++j) s8[j] = p[2 * j] + p[2 * j + 1];
#pragma unroll
        for (int j = 0; j < 4; ++j) s4[j] = s8[2 * j] + s8[2 * j + 1];
        float rs = (s4[0] + s4[1]) + (s4[2] + s4[3]);
        rs += __shfl_xor(rs, 32, 64);
        l += rs;

        unsigned w0 = cvtpk_bf16(p[0], p[1]), w1 = cvtpk_bf16(p[2], p[3]);
        unsigned w2 = cvtpk_bf16(p[4], p[5]), w3 = cvtpk_bf16(p[6], p[7]);
        unsigned w4 = cvtpk_bf16(p[8], p[9]), w5 = cvtpk_bf16(p[10], p[11]);
        unsigned w6 = cvtpk_bf16(p[12], p[13]), w7 = cvtpk_bf16(p[14], p[15]);
        PSWAP(w0, w2); PSWAP(w1, w3); PSWAP(w4, w6); PSWAP(w5, w7);
        P0.u[0] = w0; P0.u[1] = w1; P0.u[2] = w2; P0.u[3] = w3;  // kv 8hi+0..7
        P1.u[0] = w4; P1.u[1] = w5; P1.u[2] = w6; P1.u[3] = w7;  // kv 16+8hi+..
    };

    // phase 3: O^T += V^T-tile x P^T (4 MFMA)
    auto PV = [&](int cur, int s, const PB& P0, const PB& P1, f32x16& oA,
                  f32x16& oB) {
        const unsigned short* vf0 = &Vs[cur][s * 1024 + lane * 8];          // dh=0
        const unsigned short* vf1 = &Vs[cur][2048 + s * 1024 + lane * 8];   // dh=1
        oA = __builtin_amdgcn_mfma_f32_32x32x16_bf16(
            *(const bf16x8*)(vf0), P0.v, oA, 0, 0, 0);
        oA = __builtin_amdgcn_mfma_f32_32x32x16_bf16(
            *(const bf16x8*)(vf0 + 512), P1.v, oA, 0, 0, 0);
        oB = __builtin_amdgcn_mfma_f32_32x32x16_bf16(
            *(const bf16x8*)(vf1), P0.v, oB, 0, 0, 0);
        oB = __builtin_amdgcn_mfma_f32_32x32x16_bf16(
            *(const bf16x8*)(vf1 + 512), P1.v, oB, 0, 0, 0);
    };

    STAGE(0, 0);
    int cur = 0;
    for (int it = 0; it < 32; ++it) {
        STAGE(cur ^ 1, ((it + 1) & 31) * 64);  // prefetch next (last wraps, unused)
        asm volatile("s_waitcnt vmcnt(4)" ::: "memory");  // cur's 4 loads done
        __builtin_amdgcn_s_barrier();
        __builtin_amdgcn_sched_barrier(0);
        // one scheduling region: two independent chains per phase
        __builtin_amdgcn_s_setprio(1);
        f32x16 st0 = QK(cur, 0);
        f32x16 st1 = QK(cur, 1);
        __builtin_amdgcn_s_setprio(0);
        PB P00, P01, P10, P11;
        SM(st0, m0, l0, oA0, oB0, P00, P01);
        SM(st1, m1, l1, oA1, oB1, P10, P11);
        __builtin_amdgcn_s_setprio(1);
        PV(cur, 0, P00, P01, oA0, oB0);
        PV(cur, 1, P10, P11, oA1, oB1);
        __builtin_amdgcn_s_setprio(0);
        __builtin_amdgcn_sched_barrier(0);
        asm volatile("" ::: "memory");
        __builtin_amdgcn_s_barrier();  // all waves done reading cur
        cur ^= 1;
    }

    // merge streams + epilogue: lane q holds O^T[d][q], d=(r&3)+8*(r>>2)+4*hi
    float mt = fmaxf(m0, m1);
    float a0 = exp2_fast(m0 - mt), a1 = exp2_fast(m1 - mt);
    float inv = 1.0f / (l0 * a0 + l1 * a1);
    unsigned short* op = AO + (size_t)(b * NSEQ + qbase + q31) * DDIM + h * HDIM;
#pragma unroll
    for (int r2 = 0; r2 < 16; ++r2) {
        int d = (r2 & 3) + 8 * (r2 >> 2) + 4 * hi;
        op[d] = f2bf((oA0[r2] * a0 + oA1[r2] * a1) * inv);
        op[d + 32] = f2bf((oB0[r2] * a0 + oB1[r2] * a1) * inv);
    }
}

// ---------------- host launch ----------------
extern "C" void kernel_launch(void* const* d_in, const int* in_sizes, int n_in,
                              void* d_out, int out_size, void* d_ws, size_t ws_size,
                              hipStream_t stream) {
    const float* q = (const float*)d_in[0];
    const float* k = (const float*)d_in[1];
    const float* v = (const float*)d_in[2];
    const float* Wq = (const float*)d_in[3];
    const float* bq = (const float*)d_in[4];
    const float* Wk = (const float*)d_in[5];
    const float* bk = (const float*)d_in[6];
    const float* Wv = (const float*)d_in[7];
    const float* bv = (const float*)d_in[8];
    const float* Wo = (const float*)d_in[9];
    const float* bo = (const float*)d_in[10];
    float* out = (float*)d_out;

    unsigned short* ws = (unsigned short*)d_ws;
    const size_t TOKD = (size_t)NTOK * DDIM;  // 4,194,304
    const size_t WD = (size_t)DDIM * DDIM;    // 1,048,576
    unsigned short* Wqb = ws;
    unsigned short* Wkb = Wqb + WD;
    unsigned short* Wvb = Wkb + WD;
    unsigned short* Wob = Wvb + WD;
    unsigned short* Qp = Wob + WD;
    unsigned short* Kp = Qp + TOKD;   // head-major K [32][2048][64]
    unsigned short* Vp = Kp + TOKD;   // head-major V^T [32][64][2048] (fused)
    unsigned short* AOp = Vp + TOKD;

    const int w8 = (int)(WD / 8);      // 131072
    cvt_w_kernel<<<dim3(w8 / 256, 1, 4), 256, 0, stream>>>(Wq, Wk, Wv, Wo,
                                                           Wqb, Wkb, Wvb, Wob);
    gemm_qkv_kernel<<<dim3(8, 32, 3), 256, 0, stream>>>(q, k, v, Wqb, Wkb, Wvb,
                                                        bq, bk, bv, Qp, Kp, Vp);
    attn_kernel<<<512, 256, 0, stream>>>(Qp, Kp, Vp, AOp);
    gemm_out_kernel<<<dim3(8, 32), 256, 0, stream>>>(AOp, Wob, bo, out);
}